// Round 15
// baseline (205.049 us; speedup 1.0000x reference)
//
#include <hip/hip_runtime.h>
#include <hip/hip_bf16.h>
#include <stdint.h>

// ---- problem constants ----
#define BB 64
#define NN 320
#define CC 768
#define HH 12
#define DH 64
#define NC3 2304
#define MROWS (BB*NN)   // 20480

typedef __attribute__((ext_vector_type(8))) short short8;
typedef __attribute__((ext_vector_type(4))) float f32x4;
typedef __attribute__((ext_vector_type(8))) __bf16 bf16x8;

union BF8U { short8 s; bf16x8 b; };
static __device__ __forceinline__ bf16x8 asbf(short8 v){ BF8U u; u.s = v; return u.b; }

#define MFMA16(a,b,c) __builtin_amdgcn_mfma_f32_16x16x32_bf16((a),(b),(c),0,0,0)

// async global->LDS, 16B per lane; LDS dest = wave-uniform base + lane*16
static __device__ __forceinline__ void gload16(const void* g, void* l){
  __builtin_amdgcn_global_load_lds(
      (const __attribute__((address_space(1))) void*)g,
      (__attribute__((address_space(3))) void*)l, 16, 0, 0);
}

// ------------------------------------------------------------------
// Kernel 0 (r15): all fp32->bf16 conversions fused into ONE launch.
//   blocks [0, XB)            : x row-major convert (8 elems/thread)
//   blocks [XB, XB+QTB)       : W_qkv transpose-convert (64x64 tiles)
//   blocks [XB+QTB, ...)      : W_proj transpose-convert
// ------------------------------------------------------------------
#define XB  (MROWS*CC/2048)    // 7680
#define QTX (NC3/64)           // 36
#define QTB (QTX*(CC/64))      // 432
#define PTX (CC/64)            // 12
#define PTB (PTX*(CC/64))      // 144

__global__ __launch_bounds__(256) void convert_all(
    const float* __restrict__ X, const float* __restrict__ Wqkv,
    const float* __restrict__ Wproj,
    __hip_bfloat16* __restrict__ Xb, __hip_bfloat16* __restrict__ wqkvT,
    __hip_bfloat16* __restrict__ wprojT)
{
  __shared__ __hip_bfloat16 t[64][72];   // +8 pad (transpose path)
  int bid = blockIdx.x;
  const int tid = threadIdx.x;

  if (bid < XB){
    size_t i = ((size_t)bid * 256 + tid) * 8;
    float4 a = *reinterpret_cast<const float4*>(&X[i]);
    float4 b = *reinterpret_cast<const float4*>(&X[i + 4]);
    __hip_bfloat16 tt[8] = {__float2bfloat16(a.x), __float2bfloat16(a.y),
                            __float2bfloat16(a.z), __float2bfloat16(a.w),
                            __float2bfloat16(b.x), __float2bfloat16(b.y),
                            __float2bfloat16(b.z), __float2bfloat16(b.w)};
    *reinterpret_cast<short8*>(&Xb[i]) = *reinterpret_cast<const short8*>(tt);
    return;
  }
  bid -= XB;
  const float* in; __hip_bfloat16* outT; int K, Nc, n0, k0;
  if (bid < QTB){ in = Wqkv;  outT = wqkvT;  K = CC; Nc = NC3;
                  n0 = (bid % QTX) * 64; k0 = (bid / QTX) * 64; }
  else { bid -= QTB; in = Wproj; outT = wprojT; K = CC; Nc = CC;
         n0 = (bid % PTX) * 64; k0 = (bid / PTX) * 64; }

  const int tx = tid & 15, ty = tid >> 4;          // 16 x 16
  #pragma unroll
  for (int i = 0; i < 4; ++i){
    int kl = ty + i * 16;
    float4 v = *reinterpret_cast<const float4*>(&in[(size_t)(k0 + kl) * Nc + n0 + tx * 4]);
    t[tx*4+0][kl] = __float2bfloat16(v.x);
    t[tx*4+1][kl] = __float2bfloat16(v.y);
    t[tx*4+2][kl] = __float2bfloat16(v.z);
    t[tx*4+3][kl] = __float2bfloat16(v.w);
  }
  __syncthreads();
  #pragma unroll
  for (int j = 0; j < 2; ++j){
    int nl = (tid >> 3) + j * 32;
    int kl = (tid & 7) * 8;
    short8 v = *reinterpret_cast<const short8*>(&t[nl][kl]);
    *reinterpret_cast<short8*>(&outT[(size_t)(n0 + nl) * K + k0 + kl]) = v;
  }
}

// ------------------------------------------------------------------
// GEMM (r14 frozen): 128x128 tile, BK=64, 4 waves, single-buffered
// 32KB LDS, __launch_bounds__(256,4) = 4 blocks/CU. ~74% of the
// LDS-throughput floor for this geometry (m97-class ceiling).
// ------------------------------------------------------------------
#define BM 128
#define BN 128
#define BK 64
#define NT (CC/BK)   // 12

__global__ __launch_bounds__(256, 4) void gemm_qkv(
    const __hip_bfloat16* __restrict__ Xb,       // [20480][768]
    const __hip_bfloat16* __restrict__ WT,       // [2304][768]
    __hip_bfloat16* __restrict__ qb,
    __hip_bfloat16* __restrict__ kb,
    __hip_bfloat16* __restrict__ vt)
{
  __shared__ __hip_bfloat16 As[BM][BK];   // 16 KB, linear (gload_lds dest)
  __shared__ __hip_bfloat16 Bs[BN][BK];   // 16 KB
  const int tid = threadIdx.x;
  const int bm = blockIdx.x * BM;
  const int bn = blockIdx.y * BN;
  const int w = tid >> 6, lane = tid & 63;
  const int wr = w >> 1, wc = w & 1;
  const int l16 = lane & 15, lq = lane >> 4;
  const int srow = lane >> 3;                          // 0..7 within chunk
  const int scol = ((lane & 7) ^ srow) * 8;            // pre-swizzled global col (elems)
  const int rsw  = (l16 & 7) * 8;                      // read-side XOR (elems)

  f32x4 acc[4][4];
  #pragma unroll
  for (int i = 0; i < 4; ++i)
    #pragma unroll
    for (int j = 0; j < 4; ++j) acc[i][j] = (f32x4){0.f,0.f,0.f,0.f};

  for (int k0 = 0; k0 < CC; k0 += BK){
    #pragma unroll
    for (int it = 0; it < 4; ++it){
      int c = w * 4 + it;                 // 0..15, 8 rows per 1KB chunk
      int row = c * 8 + srow;
      gload16(&Xb[(size_t)(bm + row) * CC + k0 + scol], &As[0][0] + c * 512);
      gload16(&WT[(size_t)(bn + row) * CC + k0 + scol], &Bs[0][0] + c * 512);
    }
    __syncthreads();   // vmcnt(0) drain + barrier: tile ready
    #pragma unroll
    for (int kc = 0; kc < 2; ++kc){
      const int acol = (kc*32 + lq*8) ^ rsw;
      short8 bfr[4];
      #pragma unroll
      for (int ni = 0; ni < 4; ++ni)
        bfr[ni] = *reinterpret_cast<const short8*>(&Bs[wc*64 + ni*16 + l16][acol]);
      #pragma unroll
      for (int mi = 0; mi < 4; ++mi){
        short8 af = *reinterpret_cast<const short8*>(&As[wr*64 + mi*16 + l16][acol]);
        #pragma unroll
        for (int ni = 0; ni < 4; ++ni)
          acc[mi][ni] = MFMA16(asbf(af), asbf(bfr[ni]), acc[mi][ni]);
      }
    }
    __syncthreads();   // compute done before next stage overwrites
  }

  // ---- epilogue: uniform-branch scatter (r12) ----
  const int s = bn / CC;                          // block-uniform
  const int h = ((bn % CC) >> 6) + wc;            // wave-uniform
  if (s == 2){
    #pragma unroll
    for (int mi = 0; mi < 4; ++mi){
      const int rowbase = bm + wr*64 + mi*16 + lq*4;
      const int b  = rowbase / NN;
      const int n0 = rowbase - b * NN;
      const int bh = b * HH + h;
      #pragma unroll
      for (int ni = 0; ni < 4; ++ni){
        const int dh = ni*16 + l16;
        __hip_bfloat16 q4[4] = {__float2bfloat16(acc[mi][ni][0]),
                                __float2bfloat16(acc[mi][ni][1]),
                                __float2bfloat16(acc[mi][ni][2]),
                                __float2bfloat16(acc[mi][ni][3])};
        *reinterpret_cast<uint64_t*>(&vt[((size_t)bh * DH + dh) * NN + n0]) =
            *reinterpret_cast<const uint64_t*>(q4);
      }
    }
  } else {
    __hip_bfloat16* const dst = (s == 0) ? qb : kb;
    #pragma unroll
    for (int mi = 0; mi < 4; ++mi){
      const int rowbase = bm + wr*64 + mi*16 + lq*4;
      const int b  = rowbase / NN;
      const int n0 = rowbase - b * NN;
      const int bh = b * HH + h;
      #pragma unroll
      for (int r = 0; r < 4; ++r){
        __hip_bfloat16* rp = dst + ((size_t)bh * NN + n0 + r) * DH + l16;
        #pragma unroll
        for (int ni = 0; ni < 4; ++ni)
          rp[ni*16] = __float2bfloat16(acc[mi][ni][r]);
      }
    }
  }
}

// ------------------------------------------------------------------
// Kernel 2 (r15 rewrite): ONLINE-SOFTMAX attention, single pass over
// kv tiles. Removes s[NKT] (80 VGPR at NKT=20) -> ~100 regs <= 128 =>
// up to 16 waves/CU; LDS = K dbuf 16K + V dbuf 16K + P 9.2K = 41.2KB
// -> 3 blocks/CU (12 waves, 1.5x r14's TLP). Barriers 20 -> 10/block.
// Staging: r9-proven counted ledger — prologue stages (K0,V0,K1,V1)=8
// outstanding; per iter entry vmcnt(4) (next tile's 4 stay in flight),
// tail vmcnt(0); stages issued only after the consume-barrier.
// Numerics: P and l both use bf16-rounded p; rescale f=exp(m_old-m_new)
// applied identically to o and l (consistent ratio).
// ------------------------------------------------------------------
template<int NKT>
__global__ __launch_bounds__(256, 4) void attn_kernel(
    const __hip_bfloat16* __restrict__ qb,
    const __hip_bfloat16* __restrict__ kb,
    const __hip_bfloat16* __restrict__ vt,
    __hip_bfloat16* __restrict__ ob)
{
  constexpr int NTILE = NKT / 4;              // 64-kv tiles: 5 (s) or 1 (mt)
  constexpr int NBUF  = (NTILE > 1) ? 2 : 1;
  __shared__ __hip_bfloat16 Kt[NBUF][64][64];
  __shared__ __hip_bfloat16 Vt[NBUF][64][64];
  __shared__ __hip_bfloat16 P[4][16][72];     // per-wave P tile, +8 pad

  const int tid = threadIdx.x;
  const int w = tid >> 6, lane = tid & 63;
  const int l16 = lane & 15, lq = lane >> 4;
  const int srow = lane >> 3;                    // 0..7
  const int scol = ((lane & 7) ^ srow) * 8;      // pre-swizzled source col
  const int rsw  = (l16 & 7) * 8;                // read-side XOR

  int bh, qbase;
  if (NKT == 4){ bh = blockIdx.x;      qbase = 0; }
  else         { bh = blockIdx.x >> 2; qbase = 64 + (blockIdx.x & 3) * 64; }
  const int qrow0 = qbase + w * 16;

  const __hip_bfloat16* qp = qb + ((size_t)bh * NN + qrow0) * DH;
  const __hip_bfloat16* kp = kb + (size_t)bh * NN * DH;
  const __hip_bfloat16* vp = vt + (size_t)bh * DH * NN;

  // Q fragments (held for whole kernel); pin before staging
  short8 aq[2];
  #pragma unroll
  for (int kc = 0; kc < 2; ++kc)
    aq[kc] = *reinterpret_cast<const short8*>(&qp[l16 * DH + kc*32 + lq*8]);
  __builtin_amdgcn_sched_barrier(0);

  auto stageK = [&](int j){
    #pragma unroll
    for (int it = 0; it < 2; ++it){
      int c = w * 2 + it;
      gload16(&kp[(size_t)(j*64 + c*8 + srow) * DH + scol],
              &Kt[j & (NBUF-1)][0][0] + c * 512);
    }
  };
  auto stageV = [&](int j){
    #pragma unroll
    for (int it = 0; it < 2; ++it){
      int c = w * 2 + it;
      gload16(&vp[(size_t)(c*8 + srow) * NN + j*64 + scol],
              &Vt[j & (NBUF-1)][0][0] + c * 512);
    }
  };

  float m[4] = {-1e30f, -1e30f, -1e30f, -1e30f};
  float l[4] = {0.f, 0.f, 0.f, 0.f};
  f32x4 o[4];
  #pragma unroll
  for (int nt = 0; nt < 4; ++nt) o[nt] = (f32x4){0.f,0.f,0.f,0.f};

  const float scale = 0.125f;

  stageK(0); stageV(0);
  if (NTILE > 1){ stageK(1); stageV(1); }

  #pragma unroll
  for (int j = 0; j < NTILE; ++j){
    if (j + 1 < NTILE) asm volatile("s_waitcnt vmcnt(4)" ::: "memory");
    else               asm volatile("s_waitcnt vmcnt(0)" ::: "memory");
    __builtin_amdgcn_s_barrier();              // K[j],V[j] ready for all waves

    // ---- QK^T on tile j ----
    f32x4 st[4];
    #pragma unroll
    for (int ktl = 0; ktl < 4; ++ktl) st[ktl] = (f32x4){0.f,0.f,0.f,0.f};
    #pragma unroll
    for (int kc = 0; kc < 2; ++kc){
      const int acol = (kc*32 + lq*8) ^ rsw;
      #pragma unroll
      for (int ktl = 0; ktl < 4; ++ktl){
        short8 bk = *reinterpret_cast<const short8*>(&Kt[j & (NBUF-1)][ktl*16 + l16][acol]);
        st[ktl] = MFMA16(asbf(aq[kc]), asbf(bk), st[ktl]);
      }
    }

    // ---- online softmax update (per row r) ----
    float f[4];
    #pragma unroll
    for (int r = 0; r < 4; ++r){
      float tmax = fmaxf(fmaxf(st[0][r], st[1][r]), fmaxf(st[2][r], st[3][r]));
      #pragma unroll
      for (int off = 1; off < 16; off <<= 1) tmax = fmaxf(tmax, __shfl_xor(tmax, off));
      float mnew = fmaxf(m[r], tmax * scale);
      f[r] = __expf(m[r] - mnew);
      float sm = 0.f;
      #pragma unroll
      for (int ktl = 0; ktl < 4; ++ktl){
        float p = __expf(st[ktl][r] * scale - mnew);
        __hip_bfloat16 pb = __float2bfloat16(p);
        P[w][lq*4 + r][ktl*16 + l16] = pb;
        sm += __bfloat162float(pb);            // denominator consistent with P
      }
      #pragma unroll
      for (int off = 1; off < 16; off <<= 1) sm += __shfl_xor(sm, off);
      l[r] = l[r] * f[r] + sm;
      m[r] = mnew;
    }
    // rescale running O
    #pragma unroll
    for (int nt = 0; nt < 4; ++nt){
      o[nt][0] *= f[0]; o[nt][1] *= f[1]; o[nt][2] *= f[2]; o[nt][3] *= f[3];
    }

    // ---- PV on tile j (P round-trip is same-wave; compiler inserts lgkm wait) ----
    #pragma unroll
    for (int kc = 0; kc < 2; ++kc){
      short8 ap = *reinterpret_cast<const short8*>(&P[w][l16][kc*32 + lq*8]);
      const int vcol = (kc*32 + lq*8) ^ rsw;
      #pragma unroll
      for (int nt = 0; nt < 4; ++nt){
        short8 bv = *reinterpret_cast<const short8*>(&Vt[j & (NBUF-1)][nt*16 + l16][vcol]);
        o[nt] = MFMA16(asbf(ap), asbf(bv), o[nt]);
      }
    }

    __builtin_amdgcn_s_barrier();              // all waves done with K[j],V[j]
    if (j + 2 < NTILE){ stageK(j + 2); stageV(j + 2); }
  }

  // write o / l -> ob[b*320 + qrow][h*64 + dh]
  const int b = bh / HH, h = bh % HH;
  #pragma unroll
  for (int nt = 0; nt < 4; ++nt){
    #pragma unroll
    for (int r = 0; r < 4; ++r){
      int qrow = qrow0 + lq*4 + r;
      int dh = nt*16 + l16;
      float val = o[nt][r] / l[r];
      ob[((size_t)b * NN + qrow) * CC + h * DH + dh] = __float2bfloat16(val);
    }
  }
}

// ------------------------------------------------------------------
// Kernel 3: proj GEMM (M=20480, K=768, N=768) + bias, fp32 out.
// r14 frozen, launch_bounds(256,4).
// ------------------------------------------------------------------
__global__ __launch_bounds__(256, 4) void gemm_proj(
    const __hip_bfloat16* __restrict__ A,        // [20480][768] bf16
    const __hip_bfloat16* __restrict__ WT,       // [768][768] bf16 (transposed)
    const float* __restrict__ bias,
    float* __restrict__ out)
{
  __shared__ __hip_bfloat16 As[BM][BK];
  __shared__ __hip_bfloat16 Bs[BN][BK];
  const int tid = threadIdx.x;
  const int bm = blockIdx.x * BM;
  const int bn = blockIdx.y * BN;
  const int w = tid >> 6, lane = tid & 63;
  const int wr = w >> 1, wc = w & 1;
  const int l16 = lane & 15, lq = lane >> 4;
  const int srow = lane >> 3;
  const int scol = ((lane & 7) ^ srow) * 8;
  const int rsw  = (l16 & 7) * 8;

  f32x4 acc[4][4];
  #pragma unroll
  for (int i = 0; i < 4; ++i)
    #pragma unroll
    for (int j = 0; j < 4; ++j) acc[i][j] = (f32x4){0.f,0.f,0.f,0.f};

  for (int k0 = 0; k0 < CC; k0 += BK){
    #pragma unroll
    for (int it = 0; it < 4; ++it){
      int c = w * 4 + it;
      int row = c * 8 + srow;
      gload16(&A [(size_t)(bm + row) * CC + k0 + scol], &As[0][0] + c * 512);
      gload16(&WT[(size_t)(bn + row) * CC + k0 + scol], &Bs[0][0] + c * 512);
    }
    __syncthreads();
    #pragma unroll
    for (int kc = 0; kc < 2; ++kc){
      const int acol = (kc*32 + lq*8) ^ rsw;
      short8 bfr[4];
      #pragma unroll
      for (int ni = 0; ni < 4; ++ni)
        bfr[ni] = *reinterpret_cast<const short8*>(&Bs[wc*64 + ni*16 + l16][acol]);
      #pragma unroll
      for (int mi = 0; mi < 4; ++mi){
        short8 af = *reinterpret_cast<const short8*>(&As[wr*64 + mi*16 + l16][acol]);
        #pragma unroll
        for (int ni = 0; ni < 4; ++ni)
          acc[mi][ni] = MFMA16(asbf(af), asbf(bfr[ni]), acc[mi][ni]);
      }
    }
    __syncthreads();
  }

  #pragma unroll
  for (int mi = 0; mi < 4; ++mi){
    #pragma unroll
    for (int ni = 0; ni < 4; ++ni){
      #pragma unroll
      for (int r = 0; r < 4; ++r){
        int row = bm + wr*64 + mi*16 + lq*4 + r;
        int col = bn + wc*64 + ni*16 + l16;
        out[(size_t)row * CC + col] = acc[mi][ni][r] + bias[col];
      }
    }
  }
}

// ------------------------------------------------------------------
extern "C" void kernel_launch(void* const* d_in, const int* in_sizes, int n_in,
                              void* d_out, int out_size, void* d_ws, size_t ws_size,
                              hipStream_t stream)
{
  const float* x     = (const float*)d_in[0];
  const float* Wqkv  = (const float*)d_in[1];
  const float* Wproj = (const float*)d_in[2];
  const float* bproj = (const float*)d_in[3];
  float* out = (float*)d_out;

  char* ws = (char*)d_ws;
  __hip_bfloat16* wqkvT  = (__hip_bfloat16*)ws; ws += (size_t)NC3 * CC * 2;      // 3.54 MB
  __hip_bfloat16* wprojT = (__hip_bfloat16*)ws; ws += (size_t)CC * CC * 2;       // 1.18 MB
  __hip_bfloat16* xb     = (__hip_bfloat16*)ws; ws += (size_t)MROWS * CC * 2;    // 31.46 MB
  const size_t headsz = (size_t)BB * HH * NN * DH * 2;                           // 31.46 MB
  __hip_bfloat16* qb = (__hip_bfloat16*)ws; ws += headsz;
  __hip_bfloat16* kb = (__hip_bfloat16*)ws; ws += headsz;
  __hip_bfloat16* vt = (__hip_bfloat16*)ws; ws += headsz;
  __hip_bfloat16* ob = (__hip_bfloat16*)ws; ws += headsz;

  // 0) all converts in one launch
  convert_all<<<XB + QTB + PTB, 256, 0, stream>>>(x, Wqkv, Wproj, xb, wqkvT, wprojT);
  // 1) qkv GEMM + scatter
  gemm_qkv<<<dim3(MROWS / BM, NC3 / BN), 256, 0, stream>>>(xb, wqkvT, qb, kb, vt);
  // 2) attention: mt (q 0..63, kv 64) and s (q 64..319, kv 320)
  attn_kernel<4><<<BB * HH, 256, 0, stream>>>(qb, kb, vt, ob);
  attn_kernel<20><<<BB * HH * 4, 256, 0, stream>>>(qb, kb, vt, ob);
  // 3) proj GEMM + bias
  gemm_proj<<<dim3(MROWS / BM, CC / BN), 256, 0, stream>>>(ob, wprojT, bproj, out);
}

// Round 17
// 196.175 us; speedup vs baseline: 1.0452x; 1.0452x over previous
//
#include <hip/hip_runtime.h>
#include <hip/hip_bf16.h>
#include <stdint.h>

// ---- problem constants ----
#define BB 64
#define NN 320
#define CC 768
#define HH 12
#define DH 64
#define NC3 2304
#define MROWS (BB*NN)   // 20480

typedef __attribute__((ext_vector_type(8))) short short8;
typedef __attribute__((ext_vector_type(4))) float f32x4;
typedef __attribute__((ext_vector_type(8))) __bf16 bf16x8;

union BF8U { short8 s; bf16x8 b; };
static __device__ __forceinline__ bf16x8 asbf(short8 v){ BF8U u; u.s = v; return u.b; }

#define MFMA16(a,b,c) __builtin_amdgcn_mfma_f32_16x16x32_bf16((a),(b),(c),0,0,0)

// async global->LDS, 16B per lane; LDS dest = wave-uniform base + lane*16
static __device__ __forceinline__ void gload16(const void* g, void* l){
  __builtin_amdgcn_global_load_lds(
      (const __attribute__((address_space(1))) void*)g,
      (__attribute__((address_space(3))) void*)l, 16, 0, 0);
}

// barrier with explicit compiler memory fences: prevents the optimizer
// from moving LDS/global-lds ops across the rendezvous (bare
// __builtin_amdgcn_s_barrier is not guaranteed to be a compiler fence;
// r16's replay-only failure is consistent with scheduling-dependent
// reordering across it).
static __device__ __forceinline__ void fenced_barrier(){
  asm volatile("" ::: "memory");
  __builtin_amdgcn_s_barrier();
  asm volatile("" ::: "memory");
}

// ------------------------------------------------------------------
// Kernel 0a: tiled transpose+convert  outT[n][k] = bf16(in[k][n])
// ------------------------------------------------------------------
__global__ __launch_bounds__(256) void convert_wT(
    const float* __restrict__ in, __hip_bfloat16* __restrict__ outT,
    int K, int Nc)
{
  __shared__ __hip_bfloat16 t[64][72];   // +8 pad
  const int n0 = blockIdx.x * 64, k0 = blockIdx.y * 64;
  const int tid = threadIdx.x;
  const int tx = tid & 15, ty = tid >> 4;          // 16 x 16

  #pragma unroll
  for (int i = 0; i < 4; ++i){
    int kl = ty + i * 16;
    float4 v = *reinterpret_cast<const float4*>(&in[(size_t)(k0 + kl) * Nc + n0 + tx * 4]);
    t[tx*4+0][kl] = __float2bfloat16(v.x);
    t[tx*4+1][kl] = __float2bfloat16(v.y);
    t[tx*4+2][kl] = __float2bfloat16(v.z);
    t[tx*4+3][kl] = __float2bfloat16(v.w);
  }
  __syncthreads();
  #pragma unroll
  for (int j = 0; j < 2; ++j){
    int nl = (tid >> 3) + j * 32;
    int kl = (tid & 7) * 8;
    short8 v = *reinterpret_cast<const short8*>(&t[nl][kl]);
    *reinterpret_cast<short8*>(&outT[(size_t)(n0 + nl) * K + k0 + kl]) = v;
  }
}

// ------------------------------------------------------------------
// Kernel 0b: convert x fp32 -> bf16 (row-major, same layout)
// ------------------------------------------------------------------
__global__ __launch_bounds__(256) void convert_x(
    const float* __restrict__ X, __hip_bfloat16* __restrict__ Xb)
{
  size_t i = ((size_t)blockIdx.x * 256 + threadIdx.x) * 8;
  float4 a = *reinterpret_cast<const float4*>(&X[i]);
  float4 b = *reinterpret_cast<const float4*>(&X[i + 4]);
  __hip_bfloat16 t[8] = {__float2bfloat16(a.x), __float2bfloat16(a.y),
                         __float2bfloat16(a.z), __float2bfloat16(a.w),
                         __float2bfloat16(b.x), __float2bfloat16(b.y),
                         __float2bfloat16(b.z), __float2bfloat16(b.w)};
  *reinterpret_cast<short8*>(&Xb[i]) = *reinterpret_cast<const short8*>(t);
}

// ------------------------------------------------------------------
// GEMM (r14 frozen): 128x128 tile, BK=64, 4 waves, single-buffered
// 32KB LDS, __launch_bounds__(256,4) = 4 blocks/CU.
// ------------------------------------------------------------------
#define BM 128
#define BN 128
#define BK 64
#define NT (CC/BK)   // 12

__global__ __launch_bounds__(256, 4) void gemm_qkv(
    const __hip_bfloat16* __restrict__ Xb,       // [20480][768]
    const __hip_bfloat16* __restrict__ WT,       // [2304][768]
    __hip_bfloat16* __restrict__ qb,
    __hip_bfloat16* __restrict__ kb,
    __hip_bfloat16* __restrict__ vt)
{
  __shared__ __hip_bfloat16 As[BM][BK];   // 16 KB, linear (gload_lds dest)
  __shared__ __hip_bfloat16 Bs[BN][BK];   // 16 KB
  const int tid = threadIdx.x;
  const int bm = blockIdx.x * BM;
  const int bn = blockIdx.y * BN;
  const int w = tid >> 6, lane = tid & 63;
  const int wr = w >> 1, wc = w & 1;
  const int l16 = lane & 15, lq = lane >> 4;
  const int srow = lane >> 3;                          // 0..7 within chunk
  const int scol = ((lane & 7) ^ srow) * 8;            // pre-swizzled global col (elems)
  const int rsw  = (l16 & 7) * 8;                      // read-side XOR (elems)

  f32x4 acc[4][4];
  #pragma unroll
  for (int i = 0; i < 4; ++i)
    #pragma unroll
    for (int j = 0; j < 4; ++j) acc[i][j] = (f32x4){0.f,0.f,0.f,0.f};

  for (int k0 = 0; k0 < CC; k0 += BK){
    #pragma unroll
    for (int it = 0; it < 4; ++it){
      int c = w * 4 + it;                 // 0..15, 8 rows per 1KB chunk
      int row = c * 8 + srow;
      gload16(&Xb[(size_t)(bm + row) * CC + k0 + scol], &As[0][0] + c * 512);
      gload16(&WT[(size_t)(bn + row) * CC + k0 + scol], &Bs[0][0] + c * 512);
    }
    __syncthreads();   // vmcnt(0) drain + barrier: tile ready
    #pragma unroll
    for (int kc = 0; kc < 2; ++kc){
      const int acol = (kc*32 + lq*8) ^ rsw;
      short8 bfr[4];
      #pragma unroll
      for (int ni = 0; ni < 4; ++ni)
        bfr[ni] = *reinterpret_cast<const short8*>(&Bs[wc*64 + ni*16 + l16][acol]);
      #pragma unroll
      for (int mi = 0; mi < 4; ++mi){
        short8 af = *reinterpret_cast<const short8*>(&As[wr*64 + mi*16 + l16][acol]);
        #pragma unroll
        for (int ni = 0; ni < 4; ++ni)
          acc[mi][ni] = MFMA16(asbf(af), asbf(bfr[ni]), acc[mi][ni]);
      }
    }
    __syncthreads();   // compute done before next stage overwrites
  }

  // ---- epilogue: uniform-branch scatter (r12) ----
  const int s = bn / CC;                          // block-uniform
  const int h = ((bn % CC) >> 6) + wc;            // wave-uniform
  if (s == 2){
    #pragma unroll
    for (int mi = 0; mi < 4; ++mi){
      const int rowbase = bm + wr*64 + mi*16 + lq*4;
      const int b  = rowbase / NN;
      const int n0 = rowbase - b * NN;
      const int bh = b * HH + h;
      #pragma unroll
      for (int ni = 0; ni < 4; ++ni){
        const int dh = ni*16 + l16;
        __hip_bfloat16 q4[4] = {__float2bfloat16(acc[mi][ni][0]),
                                __float2bfloat16(acc[mi][ni][1]),
                                __float2bfloat16(acc[mi][ni][2]),
                                __float2bfloat16(acc[mi][ni][3])};
        *reinterpret_cast<uint64_t*>(&vt[((size_t)bh * DH + dh) * NN + n0]) =
            *reinterpret_cast<const uint64_t*>(q4);
      }
    }
  } else {
    __hip_bfloat16* const dst = (s == 0) ? qb : kb;
    #pragma unroll
    for (int mi = 0; mi < 4; ++mi){
      const int rowbase = bm + wr*64 + mi*16 + lq*4;
      const int b  = rowbase / NN;
      const int n0 = rowbase - b * NN;
      const int bh = b * HH + h;
      #pragma unroll
      for (int r = 0; r < 4; ++r){
        __hip_bfloat16* rp = dst + ((size_t)bh * NN + n0 + r) * DH + l16;
        #pragma unroll
        for (int ni = 0; ni < 4; ++ni)
          rp[ni*16] = __float2bfloat16(acc[mi][ni][r]);
      }
    }
  }
}

// ------------------------------------------------------------------
// Kernel 2 (r14 + fenced barriers): two-phase attention, cooperative
// K/V LDS staging, counted vmcnt(2); P aliases Kt (P only written in
// phase B, after phase A's final vmcnt(0)+barrier). All raw barriers
// now carry compiler memory fences (r16 replay-race hardening).
// ------------------------------------------------------------------
template<int NKT>
__global__ __launch_bounds__(256, 4) void attn_kernel(
    const __hip_bfloat16* __restrict__ qb,
    const __hip_bfloat16* __restrict__ kb,
    const __hip_bfloat16* __restrict__ vt,
    __hip_bfloat16* __restrict__ ob)
{
  constexpr int NTILE = NKT / 4;              // 64-kv tiles: 5 (s) or 1 (mt)
  constexpr int NBUF  = (NTILE > 1) ? 2 : 1;
  constexpr int KBYTES  = NBUF * 64 * 64 * 2; // K dbuf bytes
  constexpr int PBYTES  = 4 * 16 * 72 * 2;    // 9216
  constexpr int KPBYTES = (KBYTES > PBYTES) ? KBYTES : PBYTES;
  __shared__ __align__(16) char smem[KPBYTES + NBUF * 64 * 64 * 2];
  auto Kt = reinterpret_cast<__hip_bfloat16 (*)[64][64]>(smem);           // [NBUF][64][64]
  auto P  = reinterpret_cast<__hip_bfloat16 (*)[16][72]>(smem);           // [4][16][72], aliases Kt
  auto Vt = reinterpret_cast<__hip_bfloat16 (*)[64][64]>(smem + KPBYTES); // [NBUF][64][64]

  const int tid = threadIdx.x;
  const int w = tid >> 6, lane = tid & 63;
  const int l16 = lane & 15, lq = lane >> 4;
  const int srow = lane >> 3;                    // 0..7
  const int scol = ((lane & 7) ^ srow) * 8;      // pre-swizzled source col
  const int rsw  = (l16 & 7) * 8;                // read-side XOR

  int bh, qbase;
  if (NKT == 4){ bh = blockIdx.x;      qbase = 0; }
  else         { bh = blockIdx.x >> 2; qbase = 64 + (blockIdx.x & 3) * 64; }
  const int qrow0 = qbase + w * 16;

  const __hip_bfloat16* qp = qb + ((size_t)bh * NN + qrow0) * DH;
  const __hip_bfloat16* kp = kb + (size_t)bh * NN * DH;
  const __hip_bfloat16* vp = vt + (size_t)bh * DH * NN;

  // Q fragments (held for whole kernel); pin before staging
  short8 aq[2];
  #pragma unroll
  for (int kc = 0; kc < 2; ++kc)
    aq[kc] = *reinterpret_cast<const short8*>(&qp[l16 * DH + kc*32 + lq*8]);
  __builtin_amdgcn_sched_barrier(0);

  auto stageK = [&](int j){
    #pragma unroll
    for (int it = 0; it < 2; ++it){
      int c = w * 2 + it;
      gload16(&kp[(size_t)(j*64 + c*8 + srow) * DH + scol],
              &Kt[j & (NBUF-1)][0][0] + c * 512);
    }
  };
  auto stageV = [&](int j){
    #pragma unroll
    for (int it = 0; it < 2; ++it){
      int c = w * 2 + it;
      gload16(&vp[(size_t)(c*8 + srow) * NN + j*64 + scol],
              &Vt[j & (NBUF-1)][0][0] + c * 512);
    }
  };

  f32x4 s[NKT];
  #pragma unroll
  for (int kt = 0; kt < NKT; ++kt) s[kt] = (f32x4){0.f,0.f,0.f,0.f};

  // ---- Phase A: S = Q K^T over kv tiles ----
  stageK(0);
  if (NTILE > 1) stageK(1);
  #pragma unroll
  for (int j = 0; j < NTILE; ++j){
    if (j + 1 < NTILE) asm volatile("s_waitcnt vmcnt(2)" ::: "memory");
    else               asm volatile("s_waitcnt vmcnt(0)" ::: "memory");
    fenced_barrier();                          // tile j ready for all waves
    #pragma unroll
    for (int kc = 0; kc < 2; ++kc){
      const int acol = (kc*32 + lq*8) ^ rsw;
      #pragma unroll
      for (int ktl = 0; ktl < 4; ++ktl){
        short8 bk = *reinterpret_cast<const short8*>(&Kt[j & (NBUF-1)][ktl*16 + l16][acol]);
        s[j*4 + ktl] = MFMA16(asbf(aq[kc]), asbf(bk), s[j*4 + ktl]);
      }
    }
    fenced_barrier();                          // all waves done with tile j
    if (j + 2 < NTILE) stageK(j + 2);          // overwrite j's buffer (safe)
  }

  // prefetch V tiles 0(,1) — latency hides under softmax
  stageV(0);
  if (NTILE > 1) stageV(1);

  // ---- softmax over KV cols (rows lq*4+r); logits = s * 0.125 ----
  const float scale = 0.125f;
  float sum[4];
  #pragma unroll
  for (int r = 0; r < 4; ++r){
    float mx = -1e30f;
    #pragma unroll
    for (int kt = 0; kt < NKT; ++kt) mx = fmaxf(mx, s[kt][r]);
    #pragma unroll
    for (int off = 1; off < 16; off <<= 1) mx = fmaxf(mx, __shfl_xor(mx, off));
    float sm = 0.f;
    #pragma unroll
    for (int kt = 0; kt < NKT; ++kt){
      float p = __expf((s[kt][r] - mx) * scale);
      __hip_bfloat16 pb = __float2bfloat16(p);
      s[kt][r] = __bfloat162float(pb);         // keep bf16-rounded p in regs
      sm += __bfloat162float(pb);              // denominator consistent with P
    }
    #pragma unroll
    for (int off = 1; off < 16; off <<= 1) sm += __shfl_xor(sm, off);
    sum[r] = sm;
  }

  // ---- Phase B: O = P V over kv tiles (P aliases Kt — all K reads
  //      completed: final phase-A vmcnt(0) + barriers) ----
  f32x4 o[4];
  #pragma unroll
  for (int nt = 0; nt < 4; ++nt) o[nt] = (f32x4){0.f,0.f,0.f,0.f};
  #pragma unroll
  for (int j = 0; j < NTILE; ++j){
    if (j + 1 < NTILE) asm volatile("s_waitcnt vmcnt(2)" ::: "memory");
    else               asm volatile("s_waitcnt vmcnt(0)" ::: "memory");
    fenced_barrier();                          // V tile j ready
    #pragma unroll
    for (int ktl = 0; ktl < 4; ++ktl)
      #pragma unroll
      for (int r = 0; r < 4; ++r)
        P[w][lq*4 + r][ktl*16 + l16] = __float2bfloat16(s[j*4 + ktl][r]);
    #pragma unroll
    for (int kc = 0; kc < 2; ++kc){
      short8 ap = *reinterpret_cast<const short8*>(&P[w][l16][kc*32 + lq*8]);
      const int vcol = (kc*32 + lq*8) ^ rsw;
      #pragma unroll
      for (int nt = 0; nt < 4; ++nt){
        short8 bv = *reinterpret_cast<const short8*>(&Vt[j & (NBUF-1)][nt*16 + l16][vcol]);
        o[nt] = MFMA16(asbf(ap), asbf(bv), o[nt]);
      }
    }
    fenced_barrier();                          // all waves done with V tile j
    if (j + 2 < NTILE) stageV(j + 2);
  }

  // write o / sum -> ob[b*320 + qrow][h*64 + dh]
  const int b = bh / HH, h = bh % HH;
  #pragma unroll
  for (int nt = 0; nt < 4; ++nt){
    #pragma unroll
    for (int r = 0; r < 4; ++r){
      int qrow = qrow0 + lq*4 + r;
      int dh = nt*16 + l16;
      float val = o[nt][r] / sum[r];
      ob[((size_t)b * NN + qrow) * CC + h * DH + dh] = __float2bfloat16(val);
    }
  }
}

// ------------------------------------------------------------------
// Kernel 3: proj GEMM (M=20480, K=768, N=768) + bias, fp32 out.
// r14 frozen, launch_bounds(256,4).
// ------------------------------------------------------------------
__global__ __launch_bounds__(256, 4) void gemm_proj(
    const __hip_bfloat16* __restrict__ A,        // [20480][768] bf16
    const __hip_bfloat16* __restrict__ WT,       // [768][768] bf16 (transposed)
    const float* __restrict__ bias,
    float* __restrict__ out)
{
  __shared__ __hip_bfloat16 As[BM][BK];
  __shared__ __hip_bfloat16 Bs[BN][BK];
  const int tid = threadIdx.x;
  const int bm = blockIdx.x * BM;
  const int bn = blockIdx.y * BN;
  const int w = tid >> 6, lane = tid & 63;
  const int wr = w >> 1, wc = w & 1;
  const int l16 = lane & 15, lq = lane >> 4;
  const int srow = lane >> 3;
  const int scol = ((lane & 7) ^ srow) * 8;
  const int rsw  = (l16 & 7) * 8;

  f32x4 acc[4][4];
  #pragma unroll
  for (int i = 0; i < 4; ++i)
    #pragma unroll
    for (int j = 0; j < 4; ++j) acc[i][j] = (f32x4){0.f,0.f,0.f,0.f};

  for (int k0 = 0; k0 < CC; k0 += BK){
    #pragma unroll
    for (int it = 0; it < 4; ++it){
      int c = w * 4 + it;
      int row = c * 8 + srow;
      gload16(&A [(size_t)(bm + row) * CC + k0 + scol], &As[0][0] + c * 512);
      gload16(&WT[(size_t)(bn + row) * CC + k0 + scol], &Bs[0][0] + c * 512);
    }
    __syncthreads();
    #pragma unroll
    for (int kc = 0; kc < 2; ++kc){
      const int acol = (kc*32 + lq*8) ^ rsw;
      short8 bfr[4];
      #pragma unroll
      for (int ni = 0; ni < 4; ++ni)
        bfr[ni] = *reinterpret_cast<const short8*>(&Bs[wc*64 + ni*16 + l16][acol]);
      #pragma unroll
      for (int mi = 0; mi < 4; ++mi){
        short8 af = *reinterpret_cast<const short8*>(&As[wr*64 + mi*16 + l16][acol]);
        #pragma unroll
        for (int ni = 0; ni < 4; ++ni)
          acc[mi][ni] = MFMA16(asbf(af), asbf(bfr[ni]), acc[mi][ni]);
      }
    }
    __syncthreads();
  }

  #pragma unroll
  for (int mi = 0; mi < 4; ++mi){
    #pragma unroll
    for (int ni = 0; ni < 4; ++ni){
      #pragma unroll
      for (int r = 0; r < 4; ++r){
        int row = bm + wr*64 + mi*16 + lq*4 + r;
        int col = bn + wc*64 + ni*16 + l16;
        out[(size_t)row * CC + col] = acc[mi][ni][r] + bias[col];
      }
    }
  }
}

// ------------------------------------------------------------------
extern "C" void kernel_launch(void* const* d_in, const int* in_sizes, int n_in,
                              void* d_out, int out_size, void* d_ws, size_t ws_size,
                              hipStream_t stream)
{
  const float* x     = (const float*)d_in[0];
  const float* Wqkv  = (const float*)d_in[1];
  const float* Wproj = (const float*)d_in[2];
  const float* bproj = (const float*)d_in[3];
  float* out = (float*)d_out;

  char* ws = (char*)d_ws;
  __hip_bfloat16* wqkvT  = (__hip_bfloat16*)ws; ws += (size_t)NC3 * CC * 2;      // 3.54 MB
  __hip_bfloat16* wprojT = (__hip_bfloat16*)ws; ws += (size_t)CC * CC * 2;       // 1.18 MB
  __hip_bfloat16* xb     = (__hip_bfloat16*)ws; ws += (size_t)MROWS * CC * 2;    // 31.46 MB
  const size_t headsz = (size_t)BB * HH * NN * DH * 2;                           // 31.46 MB
  __hip_bfloat16* qb = (__hip_bfloat16*)ws; ws += headsz;
  __hip_bfloat16* kb = (__hip_bfloat16*)ws; ws += headsz;
  __hip_bfloat16* vt = (__hip_bfloat16*)ws; ws += headsz;
  __hip_bfloat16* ob = (__hip_bfloat16*)ws; ws += headsz;

  // 0) weights + x -> bf16 (separate launches, r14 configuration)
  convert_wT<<<dim3(NC3/64, CC/64), 256, 0, stream>>>(Wqkv, wqkvT, CC, NC3);
  convert_wT<<<dim3(CC/64,  CC/64), 256, 0, stream>>>(Wproj, wprojT, CC, CC);
  convert_x<<<MROWS * CC / (256*8), 256, 0, stream>>>(x, xb);
  // 1) qkv GEMM + scatter
  gemm_qkv<<<dim3(MROWS / BM, NC3 / BN), 256, 0, stream>>>(xb, wqkvT, qb, kb, vt);
  // 2) attention: mt (q 0..63, kv 64) and s (q 64..319, kv 320)
  attn_kernel<4><<<BB * HH, 256, 0, stream>>>(qb, kb, vt, ob);
  attn_kernel<20><<<BB * HH * 4, 256, 0, stream>>>(qb, kb, vt, ob);
  // 3) proj GEMM + bias
  gemm_proj<<<dim3(MROWS / BM, CC / BN), 256, 0, stream>>>(ob, wprojT, bproj, out);
}